// Round 1
// baseline (738.172 us; speedup 1.0000x reference)
//
#include <hip/hip_runtime.h>
#include <hip/hip_bf16.h>
#include <stdint.h>

#define HIDDEN 2048
#define INTER  1408
#define NE     8
#define NTOK   4096
#define MAXT1  40   // BM=256 tiles: sum ceil(c/256) <= 32+8
#define MAXT2  72   // BM=128 tiles: sum ceil(c/128) <= 64+8

typedef __attribute__((ext_vector_type(8))) short short8;
typedef __attribute__((ext_vector_type(4))) float f32x4;

typedef const __attribute__((address_space(1))) unsigned char* gp1_t;
typedef __attribute__((address_space(3))) unsigned char* lp3_t;

__device__ __forceinline__ void lds_cp16(const void* g, void* l) {
    __builtin_amdgcn_global_load_lds((gp1_t)g, (lp3_t)l, 16, 0, 0);
}

// XOR-swizzled read of a [rows][64] bf16 LDS tile; ck = 16B-chunk index 0..7.
// Source side staged with the inverse (same) permutation -> both-sides swizzle.
__device__ __forceinline__ short8 ldswz64(const __hip_bfloat16* S, int r, int ck) {
    return *(const short8*)&S[r * 64 + ((ck ^ (r & 7)) << 3)];
}

__device__ __forceinline__ float bf2f(short s) {
    union { float f; unsigned u; } u; u.u = ((unsigned)(unsigned short)s) << 16; return u.f;
}

// ---------------- fp32 -> bf16 weight conversion (gate_up + down fused) --------
#define C1 (NE * 2 * INTER * HIDDEN / 4)
#define C2 (NE * HIDDEN * INTER / 4)
__global__ void cvt_w_kernel(const float* __restrict__ gu, const float* __restrict__ dn,
                             __hip_bfloat16* __restrict__ gub, __hip_bfloat16* __restrict__ dnb) {
    long c = (long)blockIdx.x * blockDim.x + threadIdx.x;
    const float* s; __hip_bfloat16* d; long o;
    if (c < C1) { s = gu; d = gub; o = c; }
    else        { s = dn; d = dnb; o = c - C1; }
    o *= 4;
    float4 v = *(const float4*)(s + o);
    *(__hip_bfloat162*)(d + o)     = __float22bfloat162_rn(make_float2(v.x, v.y));
    *(__hip_bfloat162*)(d + o + 2) = __float22bfloat162_rn(make_float2(v.z, v.w));
}

// ---------------- router ----------------
__global__ void router_kernel(const float* __restrict__ x, const float* __restrict__ rw,
                              int* __restrict__ counts, int* __restrict__ topk_e,
                              float* __restrict__ topk_w, __hip_bfloat16* __restrict__ xb) {
    int wave = threadIdx.x >> 6;
    int lane = threadIdx.x & 63;
    int t = blockIdx.x * 4 + wave;
    const float4* xr = (const float4*)(x + (size_t)t * HIDDEN);
    __hip_bfloat16* xbr = xb + (size_t)t * HIDDEN;
    float acc[NE] = {0.f,0.f,0.f,0.f,0.f,0.f,0.f,0.f};
    #pragma unroll
    for (int c = lane; c < HIDDEN / 4; c += 64) {
        float4 v = xr[c];
        *(__hip_bfloat162*)(xbr + c * 4)     = __float22bfloat162_rn(make_float2(v.x, v.y));
        *(__hip_bfloat162*)(xbr + c * 4 + 2) = __float22bfloat162_rn(make_float2(v.z, v.w));
        #pragma unroll
        for (int e = 0; e < NE; ++e) {
            float4 w = ((const float4*)(rw + e * HIDDEN))[c];
            acc[e] += v.x * w.x + v.y * w.y + v.z * w.z + v.w * w.w;
        }
    }
    #pragma unroll
    for (int e = 0; e < NE; ++e) {
        #pragma unroll
        for (int off = 32; off > 0; off >>= 1) acc[e] += __shfl_xor(acc[e], off, 64);
    }
    if (lane == 0) {
        int i1 = 0; float v1 = acc[0];
        for (int e = 1; e < NE; ++e) if (acc[e] > v1) { v1 = acc[e]; i1 = e; }
        int i2 = -1; float v2 = -3.0e38f;
        for (int e = 0; e < NE; ++e) if (e != i1 && acc[e] > v2) { v2 = acc[e]; i2 = e; }
        float w1 = 1.f / (1.f + expf(v2 - v1));
        float w2 = 1.f - w1;
        topk_e[t * 2 + 0] = i1; topk_e[t * 2 + 1] = i2;
        topk_w[t * 2 + 0] = w1; topk_w[t * 2 + 1] = w2;
        atomicAdd(&counts[i1], 1);
        atomicAdd(&counts[i2], 1);
    }
}

__global__ void scan_kernel(const int* __restrict__ counts, int* __restrict__ offsets,
                            int* __restrict__ cursor, int* __restrict__ tiles1,
                            int* __restrict__ tiles2, int* __restrict__ n_tiles) {
    if (threadIdx.x == 0) {
        int s = 0, nt1 = 0, nt2 = 0;
        for (int e = 0; e < NE; ++e) {
            offsets[e] = s; cursor[e] = s;
            int c = counts[e]; s += c;
            for (int mt = 0; mt * 256 < c; ++mt) tiles1[nt1++] = (e << 16) | mt;
            for (int mt = 0; mt * 128 < c; ++mt) tiles2[nt2++] = (e << 16) | mt;
        }
        n_tiles[0] = nt1;
        n_tiles[1] = nt2;
    }
}

__global__ void scatter_kernel(const int* __restrict__ topk_e, const float* __restrict__ topk_w,
                               int* __restrict__ cursor, int* __restrict__ slot_tid,
                               float* __restrict__ slot_w, int* __restrict__ tok2slot) {
    int k = blockIdx.x * blockDim.x + threadIdx.x;
    if (k >= NTOK * 2) return;
    int e = topk_e[k];
    int slot = atomicAdd(&cursor[e], 1);
    slot_tid[slot] = k >> 1;
    slot_w[slot]   = topk_w[k];
    tok2slot[k]    = slot;
}

// ---------------- GEMM1: 256x256(B-rows) tile, 8 waves (2m x 4n), wave 128x64,
// 16x16x32 MFMA, double-buffered LDS (128 KB), counted vmcnt(8) pipeline.
// B rows: [g(p*16..+15), u(p*16..+15)] repeating -> gate/up pairs lane-local.
__global__ __launch_bounds__(512, 2) void gemm1_kernel(
    const __hip_bfloat16* __restrict__ xb,
    const __hip_bfloat16* __restrict__ gub,
    const int* __restrict__ counts, const int* __restrict__ offsets,
    const int* __restrict__ tiles, const int* __restrict__ n_tiles,
    const int* __restrict__ slot_tid, const float* __restrict__ slot_w,
    __hip_bfloat16* __restrict__ h)
{
    const int ti = blockIdx.y;
    if (ti >= n_tiles[0]) return;
    const int tile = tiles[ti];
    const int e  = tile >> 16;
    const int mt = tile & 0xffff;
    const int nt = blockIdx.x;            // 0..10, 128 h-cols per block
    const int count = counts[e];
    const int off = offsets[e];

    extern __shared__ __hip_bfloat16 smem[];
    __hip_bfloat16* A0 = smem;                 // 256x64
    __hip_bfloat16* B0 = smem + 16384;         // 256x64
    __hip_bfloat16* A1 = smem + 32768;
    __hip_bfloat16* B1 = smem + 49152;

    const int tid  = threadIdx.x;
    const int wave = tid >> 6;
    const int lane = tid & 63;
    const int wm = wave >> 2, wn = wave & 3;   // 2 x 4 wave grid
    const int l15 = lane & 15;
    const int q   = lane >> 4;                 // k-quarter

    const __hip_bfloat16* asrc[4];
    const __hip_bfloat16* bsrc[4];
    #pragma unroll
    for (int j = 0; j < 4; ++j) {
        int fs  = j * 512 + tid;               // 2048 chunk-slots per matrix
        int row = fs >> 3;
        int c8  = (fs & 7) ^ (row & 7);        // pre-swizzled source chunk
        int rg  = mt * 256 + row;
        int rc  = rg < count ? rg : count - 1;
        int tok = slot_tid[off + rc];
        asrc[j] = xb + (size_t)tok * HIDDEN + c8 * 8;
        int p = row >> 5, sel = (row >> 4) & 1, idx = row & 15;
        int hc = nt * 128 + p * 16 + idx;
        int grow = sel ? (INTER + hc) : hc;
        bsrc[j] = gub + ((size_t)(e * 2 * INTER + grow)) * HIDDEN + c8 * 8;
    }

    f32x4 acc[8][4];
    #pragma unroll
    for (int mf = 0; mf < 8; ++mf)
        #pragma unroll
        for (int nf = 0; nf < 4; ++nf) acc[mf][nf] = (f32x4)0.f;

    // prologue: stage K-tile 0 into buf0
    #pragma unroll
    for (int j = 0; j < 4; ++j) lds_cp16(asrc[j], (__hip_bfloat16*)A0 + (j * 512 + tid) * 8);
    #pragma unroll
    for (int j = 0; j < 4; ++j) lds_cp16(bsrc[j], (__hip_bfloat16*)B0 + (j * 512 + tid) * 8);

    #pragma unroll 2
    for (int t = 0; t < 32; ++t) {
        const __hip_bfloat16* Ac = (t & 1) ? A1 : A0;
        const __hip_bfloat16* Bc = (t & 1) ? B1 : B0;
        __hip_bfloat16* An = (t & 1) ? A0 : A1;
        __hip_bfloat16* Bn = (t & 1) ? B0 : B1;
        if (t + 1 < 32) {
            const int k0 = (t + 1) * 64;
            #pragma unroll
            for (int j = 0; j < 4; ++j) lds_cp16(asrc[j] + k0, An + (j * 512 + tid) * 8);
            #pragma unroll
            for (int j = 0; j < 4; ++j) lds_cp16(bsrc[j] + k0, Bn + (j * 512 + tid) * 8);
            asm volatile("s_waitcnt vmcnt(8)" ::: "memory"); // current tile landed; 8 prefetch in flight
        } else {
            asm volatile("s_waitcnt vmcnt(0)" ::: "memory");
        }
        __builtin_amdgcn_sched_barrier(0);
        __builtin_amdgcn_s_barrier();
        asm volatile("" ::: "memory");
        __builtin_amdgcn_sched_barrier(0);
        #pragma unroll
        for (int kh = 0; kh < 2; ++kh) {
            const int ck = kh * 4 + q;
            short8 bfr[4], afr[8];
            #pragma unroll
            for (int nf = 0; nf < 4; ++nf) bfr[nf] = ldswz64(Bc, wn * 64 + nf * 16 + l15, ck);
            #pragma unroll
            for (int mf = 0; mf < 8; ++mf) afr[mf] = ldswz64(Ac, wm * 128 + mf * 16 + l15, ck);
            __builtin_amdgcn_s_setprio(1);
            #pragma unroll
            for (int mf = 0; mf < 8; ++mf)
                #pragma unroll
                for (int nf = 0; nf < 4; ++nf)
                    acc[mf][nf] = __builtin_amdgcn_mfma_f32_16x16x32_bf16(afr[mf], bfr[nf], acc[mf][nf], 0, 0, 0);
            __builtin_amdgcn_s_setprio(0);
        }
        __builtin_amdgcn_sched_barrier(0);
        __builtin_amdgcn_s_barrier();
        asm volatile("" ::: "memory");
        __builtin_amdgcn_sched_barrier(0);
    }

    // epilogue: D col = lane&15, row = (lane>>4)*4 + reg
    #pragma unroll
    for (int mf = 0; mf < 8; ++mf) {
        #pragma unroll
        for (int reg = 0; reg < 4; ++reg) {
            int row = wm * 128 + mf * 16 + q * 4 + reg;
            int rg  = mt * 256 + row;
            if (rg < count) {
                float wgt = slot_w[off + rg];
                #pragma unroll
                for (int g = 0; g < 2; ++g) {
                    float gv = acc[mf][2 * g + 0][reg];
                    float uv = acc[mf][2 * g + 1][reg];
                    float hv = gv / (1.f + __expf(-gv)) * uv * wgt;
                    h[(size_t)(off + rg) * INTER + nt * 128 + (wn * 2 + g) * 16 + l15] =
                        __float2bfloat16(hv);
                }
            }
        }
    }
}

// ---------------- GEMM2: 128x256 tile, 8 waves (2m x 4n), wave 64x64,
// 16x16x32 MFMA, double-buffered LDS (96 KB), counted vmcnt(6) pipeline.
__global__ __launch_bounds__(512, 2) void gemm2_kernel(
    const __hip_bfloat16* __restrict__ h,
    const __hip_bfloat16* __restrict__ dnb,
    const int* __restrict__ counts, const int* __restrict__ offsets,
    const int* __restrict__ tiles, const int* __restrict__ n_tiles,
    __hip_bfloat16* __restrict__ eo)
{
    const int ti = blockIdx.y;
    if (ti >= n_tiles[1]) return;
    const int tile = tiles[ti];
    const int e  = tile >> 16;
    const int mt = tile & 0xffff;
    const int nt = blockIdx.x;            // 0..7, 256 out-cols per block
    const int count = counts[e];
    const int off = offsets[e];

    extern __shared__ __hip_bfloat16 smem[];
    __hip_bfloat16* A0 = smem;                 // 128x64
    __hip_bfloat16* B0 = smem + 8192;          // 256x64
    __hip_bfloat16* A1 = smem + 24576;
    __hip_bfloat16* B1 = smem + 32768;

    const int tid  = threadIdx.x;
    const int wave = tid >> 6;
    const int lane = tid & 63;
    const int wm = wave >> 2, wn = wave & 3;
    const int l15 = lane & 15;
    const int q   = lane >> 4;

    const __hip_bfloat16* asrc[2];
    const __hip_bfloat16* bsrc[4];
    #pragma unroll
    for (int j = 0; j < 2; ++j) {
        int fs  = j * 512 + tid;               // 1024 chunk-slots (128 rows)
        int row = fs >> 3;
        int c8  = (fs & 7) ^ (row & 7);
        asrc[j] = h + (size_t)(off + mt * 128 + row) * INTER + c8 * 8;
    }
    #pragma unroll
    for (int j = 0; j < 4; ++j) {
        int fs  = j * 512 + tid;               // 2048 chunk-slots (256 rows)
        int row = fs >> 3;
        int c8  = (fs & 7) ^ (row & 7);
        bsrc[j] = dnb + ((size_t)(e * HIDDEN + nt * 256 + row)) * INTER + c8 * 8;
    }

    f32x4 acc[4][4];
    #pragma unroll
    for (int mf = 0; mf < 4; ++mf)
        #pragma unroll
        for (int nf = 0; nf < 4; ++nf) acc[mf][nf] = (f32x4)0.f;

    #pragma unroll
    for (int j = 0; j < 2; ++j) lds_cp16(asrc[j], (__hip_bfloat16*)A0 + (j * 512 + tid) * 8);
    #pragma unroll
    for (int j = 0; j < 4; ++j) lds_cp16(bsrc[j], (__hip_bfloat16*)B0 + (j * 512 + tid) * 8);

    #pragma unroll 2
    for (int t = 0; t < 22; ++t) {
        const __hip_bfloat16* Ac = (t & 1) ? A1 : A0;
        const __hip_bfloat16* Bc = (t & 1) ? B1 : B0;
        __hip_bfloat16* An = (t & 1) ? A0 : A1;
        __hip_bfloat16* Bn = (t & 1) ? B0 : B1;
        if (t + 1 < 22) {
            const int k0 = (t + 1) * 64;
            #pragma unroll
            for (int j = 0; j < 2; ++j) lds_cp16(asrc[j] + k0, An + (j * 512 + tid) * 8);
            #pragma unroll
            for (int j = 0; j < 4; ++j) lds_cp16(bsrc[j] + k0, Bn + (j * 512 + tid) * 8);
            asm volatile("s_waitcnt vmcnt(6)" ::: "memory");
        } else {
            asm volatile("s_waitcnt vmcnt(0)" ::: "memory");
        }
        __builtin_amdgcn_sched_barrier(0);
        __builtin_amdgcn_s_barrier();
        asm volatile("" ::: "memory");
        __builtin_amdgcn_sched_barrier(0);
        #pragma unroll
        for (int kh = 0; kh < 2; ++kh) {
            const int ck = kh * 4 + q;
            short8 bfr[4], afr[4];
            #pragma unroll
            for (int nf = 0; nf < 4; ++nf) bfr[nf] = ldswz64(Bc, wn * 64 + nf * 16 + l15, ck);
            #pragma unroll
            for (int mf = 0; mf < 4; ++mf) afr[mf] = ldswz64(Ac, wm * 64 + mf * 16 + l15, ck);
            __builtin_amdgcn_s_setprio(1);
            #pragma unroll
            for (int mf = 0; mf < 4; ++mf)
                #pragma unroll
                for (int nf = 0; nf < 4; ++nf)
                    acc[mf][nf] = __builtin_amdgcn_mfma_f32_16x16x32_bf16(afr[mf], bfr[nf], acc[mf][nf], 0, 0, 0);
            __builtin_amdgcn_s_setprio(0);
        }
        __builtin_amdgcn_sched_barrier(0);
        __builtin_amdgcn_s_barrier();
        asm volatile("" ::: "memory");
        __builtin_amdgcn_sched_barrier(0);
    }

    #pragma unroll
    for (int mf = 0; mf < 4; ++mf) {
        #pragma unroll
        for (int reg = 0; reg < 4; ++reg) {
            int row = wm * 64 + mf * 16 + q * 4 + reg;
            int rg  = mt * 128 + row;
            if (rg < count) {
                size_t base = (size_t)(off + rg) * HIDDEN + nt * 256 + wn * 64;
                #pragma unroll
                for (int nf = 0; nf < 4; ++nf)
                    eo[base + nf * 16 + l15] = __float2bfloat16(acc[mf][nf][reg]);
            }
        }
    }
}

// ---------------- combine ----------------
__global__ void combine_kernel(const __hip_bfloat16* __restrict__ eo,
                               const int* __restrict__ tok2slot,
                               float* __restrict__ out) {
    int idx = blockIdx.x * blockDim.x + threadIdx.x;
    int t = idx >> 8;
    int c = (idx & 255) * 8;
    int s1 = tok2slot[t * 2], s2 = tok2slot[t * 2 + 1];
    short8 v1 = *(const short8*)(eo + (size_t)s1 * HIDDEN + c);
    short8 v2 = *(const short8*)(eo + (size_t)s2 * HIDDEN + c);
    float4 o0, o1;
    o0.x = bf2f(v1[0]) + bf2f(v2[0]); o0.y = bf2f(v1[1]) + bf2f(v2[1]);
    o0.z = bf2f(v1[2]) + bf2f(v2[2]); o0.w = bf2f(v1[3]) + bf2f(v2[3]);
    o1.x = bf2f(v1[4]) + bf2f(v2[4]); o1.y = bf2f(v1[5]) + bf2f(v2[5]);
    o1.z = bf2f(v1[6]) + bf2f(v2[6]); o1.w = bf2f(v1[7]) + bf2f(v2[7]);
    float* op = out + (size_t)t * HIDDEN + c;
    *(float4*)op = o0;
    *(float4*)(op + 4) = o1;
}

extern "C" void kernel_launch(void* const* d_in, const int* in_sizes, int n_in,
                              void* d_out, int out_size, void* d_ws, size_t ws_size,
                              hipStream_t stream)
{
    (void)in_sizes; (void)n_in; (void)ws_size; (void)out_size;
    const float* x  = (const float*)d_in[0];
    const float* rw = (const float*)d_in[1];
    const float* gu = (const float*)d_in[2];
    const float* dn = (const float*)d_in[3];

    char* p = (char*)d_ws;
    auto take = [&](size_t bytes) { char* r = p; p += (bytes + 255) & ~(size_t)255; return r; };
    __hip_bfloat16* xb  = (__hip_bfloat16*)take((size_t)NTOK * HIDDEN * 2);
    __hip_bfloat16* gub = (__hip_bfloat16*)take((size_t)NE * 2 * INTER * HIDDEN * 2);
    __hip_bfloat16* dnb = (__hip_bfloat16*)take((size_t)NE * HIDDEN * INTER * 2);
    __hip_bfloat16* hbuf= (__hip_bfloat16*)take((size_t)(2 * NTOK + 256) * INTER * 2);
    int*   counts   = (int*)take(64);
    int*   offsets  = (int*)take(64);
    int*   cursor   = (int*)take(64);
    int*   ntile    = (int*)take(64);
    int*   tiles1   = (int*)take(MAXT1 * 4);
    int*   tiles2   = (int*)take(MAXT2 * 4);
    int*   topk_e   = (int*)take((size_t)NTOK * 2 * 4);
    float* topk_w   = (float*)take((size_t)NTOK * 2 * 4);
    int*   slot_tid = (int*)take((size_t)(2 * NTOK + 256) * 4);
    float* slot_w   = (float*)take((size_t)(2 * NTOK + 256) * 4);
    int*   tok2slot = (int*)take((size_t)NTOK * 2 * 4);
    // eo aliases gub scratch: gub dead after gemm1, eo (33.5 MB) < gub (92.3 MB)
    __hip_bfloat16* eo = gub;

    hipFuncSetAttribute((const void*)gemm1_kernel,
                        hipFuncAttributeMaxDynamicSharedMemorySize, 131072);
    hipFuncSetAttribute((const void*)gemm2_kernel,
                        hipFuncAttributeMaxDynamicSharedMemorySize, 98304);

    hipMemsetAsync(counts, 0, 64, stream);

    cvt_w_kernel<<<dim3((C1 + C2) / 256), 256, 0, stream>>>(gu, dn, gub, dnb);

    router_kernel<<<dim3(NTOK / 4), 256, 0, stream>>>(x, rw, counts, topk_e, topk_w, xb);
    scan_kernel<<<dim3(1), 64, 0, stream>>>(counts, offsets, cursor, tiles1, tiles2, ntile);
    scatter_kernel<<<dim3((NTOK * 2) / 256), 256, 0, stream>>>(topk_e, topk_w, cursor,
                                                               slot_tid, slot_w, tok2slot);

    gemm1_kernel<<<dim3(INTER / 128, MAXT1), 512, 131072, stream>>>(
        xb, gub, counts, offsets, tiles1, ntile, slot_tid, slot_w, hbuf);
    gemm2_kernel<<<dim3(HIDDEN / 256, MAXT2), 512, 98304, stream>>>(
        hbuf, dnb, counts, offsets, tiles2, ntile, eo);
    combine_kernel<<<dim3(NTOK * HIDDEN / 8 / 256), 256, 0, stream>>>(
        eo, tok2slot, (float*)d_out);
}

// Round 2
// 667.794 us; speedup vs baseline: 1.1054x; 1.1054x over previous
//
#include <hip/hip_runtime.h>
#include <hip/hip_bf16.h>
#include <stdint.h>

#define HIDDEN 2048
#define INTER  1408
#define NE     8
#define NTOK   4096
#define MAXT   40   // BM=256 tiles: sum ceil(c/256) <= 32+8

typedef __attribute__((ext_vector_type(8))) short short8;
typedef __attribute__((ext_vector_type(4))) float f32x4;

typedef const __attribute__((address_space(1))) unsigned char* gp1_t;
typedef __attribute__((address_space(3))) unsigned char* lp3_t;

__device__ __forceinline__ void lds_cp16(const void* g, void* l) {
    __builtin_amdgcn_global_load_lds((gp1_t)g, (lp3_t)l, 16, 0, 0);
}

__device__ __forceinline__ float bf2f(short s) {
    union { float f; unsigned u; } u; u.u = ((unsigned)(unsigned short)s) << 16; return u.f;
}

// ---------------- fp32 -> bf16 weight conversion (gate_up + down fused) --------
#define C1 (NE * 2 * INTER * HIDDEN / 4)
#define C2 (NE * HIDDEN * INTER / 4)
__global__ void cvt_w_kernel(const float* __restrict__ gu, const float* __restrict__ dn,
                             __hip_bfloat16* __restrict__ gub, __hip_bfloat16* __restrict__ dnb) {
    long c = (long)blockIdx.x * blockDim.x + threadIdx.x;
    const float* s; __hip_bfloat16* d; long o;
    if (c < C1) { s = gu; d = gub; o = c; }
    else        { s = dn; d = dnb; o = c - C1; }
    o *= 4;
    float4 v = *(const float4*)(s + o);
    *(__hip_bfloat162*)(d + o)     = __float22bfloat162_rn(make_float2(v.x, v.y));
    *(__hip_bfloat162*)(d + o + 2) = __float22bfloat162_rn(make_float2(v.z, v.w));
}

// ---------------- router ----------------
__global__ void router_kernel(const float* __restrict__ x, const float* __restrict__ rw,
                              int* __restrict__ counts, int* __restrict__ topk_e,
                              float* __restrict__ topk_w, __hip_bfloat16* __restrict__ xb) {
    int wave = threadIdx.x >> 6;
    int lane = threadIdx.x & 63;
    int t = blockIdx.x * 4 + wave;
    const float4* xr = (const float4*)(x + (size_t)t * HIDDEN);
    __hip_bfloat16* xbr = xb + (size_t)t * HIDDEN;
    float acc[NE] = {0.f,0.f,0.f,0.f,0.f,0.f,0.f,0.f};
    #pragma unroll
    for (int c = lane; c < HIDDEN / 4; c += 64) {
        float4 v = xr[c];
        *(__hip_bfloat162*)(xbr + c * 4)     = __float22bfloat162_rn(make_float2(v.x, v.y));
        *(__hip_bfloat162*)(xbr + c * 4 + 2) = __float22bfloat162_rn(make_float2(v.z, v.w));
        #pragma unroll
        for (int e = 0; e < NE; ++e) {
            float4 w = ((const float4*)(rw + e * HIDDEN))[c];
            acc[e] += v.x * w.x + v.y * w.y + v.z * w.z + v.w * w.w;
        }
    }
    #pragma unroll
    for (int e = 0; e < NE; ++e) {
        #pragma unroll
        for (int off = 32; off > 0; off >>= 1) acc[e] += __shfl_xor(acc[e], off, 64);
    }
    if (lane == 0) {
        int i1 = 0; float v1 = acc[0];
        for (int e = 1; e < NE; ++e) if (acc[e] > v1) { v1 = acc[e]; i1 = e; }
        int i2 = -1; float v2 = -3.0e38f;
        for (int e = 0; e < NE; ++e) if (e != i1 && acc[e] > v2) { v2 = acc[e]; i2 = e; }
        float w1 = 1.f / (1.f + expf(v2 - v1));
        float w2 = 1.f - w1;
        topk_e[t * 2 + 0] = i1; topk_e[t * 2 + 1] = i2;
        topk_w[t * 2 + 0] = w1; topk_w[t * 2 + 1] = w2;
        atomicAdd(&counts[i1], 1);
        atomicAdd(&counts[i2], 1);
    }
}

__global__ void scan_kernel(const int* __restrict__ counts, int* __restrict__ offsets,
                            int* __restrict__ cursor, int* __restrict__ tiles,
                            int* __restrict__ n_tiles) {
    if (threadIdx.x == 0) {
        int s = 0, nt = 0;
        for (int e = 0; e < NE; ++e) {
            offsets[e] = s; cursor[e] = s;
            int c = counts[e]; s += c;
            for (int mt = 0; mt * 256 < c; ++mt) tiles[nt++] = (e << 16) | mt;
        }
        n_tiles[0] = nt;
    }
}

__global__ void scatter_kernel(const int* __restrict__ topk_e, const float* __restrict__ topk_w,
                               int* __restrict__ cursor, int* __restrict__ slot_tid,
                               float* __restrict__ slot_w, int* __restrict__ tok2slot) {
    int k = blockIdx.x * blockDim.x + threadIdx.x;
    if (k >= NTOK * 2) return;
    int e = topk_e[k];
    int slot = atomicAdd(&cursor[e], 1);
    slot_tid[slot] = k >> 1;
    slot_w[slot]   = topk_w[k];
    tok2slot[k]    = slot;
}

// =====================================================================
// moe_gemm<WHICH>: BM=256 x BN=256(B-rows) x BK=64; 8 waves (2m x 4n);
// wave tile 128x64; 16x16x32 MFMA. LDS: 2 buf x {A,B} x {kh0,kh1}
// [256][32] regions (16 KB each, 128 KB total). 4-phase K-tile with
// half-tile staging (1 per phase), counted vmcnt(8), setprio MFMA.
// Pipeline (steady state):
//   P0: read A/B kh0 nf01 -> MFMA | stage [t+1 A-kh1]
//   P1: read B kh0 nf23   -> MFMA | stage [t+1 B-kh1] | vmcnt(8)
//   P2: read A/B kh1 nf01 -> MFMA | stage [t+2 A-kh0]
//   P3: read B kh1 nf23   -> MFMA | stage [t+2 B-kh0] | vmcnt(8)
// Every half-tile has >=4 phases of latency slack before its deadline.
// =====================================================================

#define FENCE asm volatile("" ::: "memory")
#define W_V8  asm volatile("s_waitcnt vmcnt(8)" ::: "memory")
#define W_V4  asm volatile("s_waitcnt vmcnt(4)" ::: "memory")
#define W_V0  asm volatile("s_waitcnt vmcnt(0)" ::: "memory")
#define W_NONE do {} while (0)
#define BAR do { __builtin_amdgcn_sched_barrier(0); FENCE; \
                 __builtin_amdgcn_s_barrier(); FENCE; } while (0)
#define LGKM0 do { asm volatile("s_waitcnt lgkmcnt(0)" ::: "memory"); \
                   __builtin_amdgcn_sched_barrier(0); } while (0)

#define DSA(Rg, mf) (*(const short8*)((Rg) + laneA + (mf) * 512))
#define DSB(Rg, nf) (*(const short8*)((Rg) + laneB + (nf) * 512))

#define MFMA16(NFP) do { \
    __builtin_amdgcn_s_setprio(1); \
    _Pragma("unroll") \
    for (int mf_ = 0; mf_ < 8; ++mf_) { \
        acc[mf_][(NFP)*2+0] = __builtin_amdgcn_mfma_f32_16x16x32_bf16(afr[mf_], bfr[0], acc[mf_][(NFP)*2+0], 0, 0, 0); \
        acc[mf_][(NFP)*2+1] = __builtin_amdgcn_mfma_f32_16x16x32_bf16(afr[mf_], bfr[1], acc[mf_][(NFP)*2+1], 0, 0, 0); \
    } \
    __builtin_amdgcn_s_setprio(0); \
    __builtin_amdgcn_sched_barrier(0); \
} while (0)

#define KTILE(T, S01, S23, W1, W3) do { \
    const int b_ = (T) & 1; \
    const __hip_bfloat16* RA0_ = smem + (((b_ << 2) | 0) << 13); \
    const __hip_bfloat16* RA1_ = smem + (((b_ << 2) | 1) << 13); \
    const __hip_bfloat16* RB0_ = smem + (((b_ << 2) | 2) << 13); \
    const __hip_bfloat16* RB1_ = smem + (((b_ << 2) | 3) << 13); \
    /* P0 */ \
    _Pragma("unroll") for (int mf_ = 0; mf_ < 8; ++mf_) afr[mf_] = DSA(RA0_, mf_); \
    bfr[0] = DSB(RB0_, 0); bfr[1] = DSB(RB0_, 1); \
    if (S01) stage(0, 1, (T) + 1, b_ ^ 1); \
    LGKM0; MFMA16(0); BAR; \
    /* P1 */ \
    bfr[0] = DSB(RB0_, 2); bfr[1] = DSB(RB0_, 3); \
    if (S01) stage(1, 1, (T) + 1, b_ ^ 1); \
    LGKM0; MFMA16(1); \
    W1; BAR; \
    /* P2 */ \
    _Pragma("unroll") for (int mf_ = 0; mf_ < 8; ++mf_) afr[mf_] = DSA(RA1_, mf_); \
    bfr[0] = DSB(RB1_, 0); bfr[1] = DSB(RB1_, 1); \
    if (S23) stage(0, 0, (T) + 2, b_); \
    LGKM0; MFMA16(0); BAR; \
    /* P3 */ \
    bfr[0] = DSB(RB1_, 2); bfr[1] = DSB(RB1_, 3); \
    if (S23) stage(1, 0, (T) + 2, b_); \
    LGKM0; MFMA16(1); \
    W3; BAR; \
} while (0)

template<int WHICH>  // 1 = gate_up+silu, 2 = down-proj
__global__ __launch_bounds__(512, 2) void moe_gemm(
    const __hip_bfloat16* __restrict__ Ag,
    const __hip_bfloat16* __restrict__ Bg,
    const int* __restrict__ counts, const int* __restrict__ offsets,
    const int* __restrict__ tiles, const int* __restrict__ n_tiles,
    const int* __restrict__ slot_tid, const float* __restrict__ slot_w,
    __hip_bfloat16* __restrict__ Out)
{
    constexpr int KDIM = (WHICH == 1) ? HIDDEN : INTER;
    constexpr int NT   = KDIM / 64;

    const int ti = blockIdx.y;
    if (ti >= n_tiles[0]) return;
    const int tile = tiles[ti];
    const int e  = tile >> 16;
    const int mt = tile & 0xffff;
    const int nt = blockIdx.x;
    const int count = counts[e];
    const int off = offsets[e];

    extern __shared__ __hip_bfloat16 smem[];

    const int tid  = threadIdx.x;
    const int wave = tid >> 6;
    const int lane = tid & 63;
    const int wm = wave >> 2, wn = wave & 3;
    const int l15 = lane & 15;
    const int q   = lane >> 4;
    const int sw  = (l15 >> 1) & 3;

    // element offsets within a [256][32] region; XOR swizzle pos = q ^ ((r>>1)&3).
    // (r>>1)&3 == (l15>>1)&3 since all row-base terms are multiples of 8 rows.
    const int laneA = (wm * 128 + l15) * 32 + ((q ^ sw) << 3);
    const int laneB = (wn * 64  + l15) * 32 + ((q ^ sw) << 3);

    // staging source pointers; thread handles chunk cs = j*512+tid of each region.
    const __hip_bfloat16* PA[2];
    const __hip_bfloat16* PB[2];
    #pragma unroll
    for (int j = 0; j < 2; ++j) {
        int cs  = j * 512 + tid;
        int row = cs >> 2;
        int kc  = (cs & 3) ^ ((row >> 1) & 3);   // inverse (== same) XOR on source
        int rg  = mt * 256 + row;
        int rc  = rg < count ? rg : count - 1;
        if constexpr (WHICH == 1) {
            int tok = slot_tid[off + rc];
            PA[j] = Ag + (size_t)tok * HIDDEN + kc * 8;
            int p = row >> 5, sel = (row >> 4) & 1, idx = row & 15;
            int hc = nt * 128 + p * 16 + idx;
            int grow = sel ? (INTER + hc) : hc;
            PB[j] = Bg + ((size_t)(e * 2 * INTER + grow)) * HIDDEN + kc * 8;
        } else {
            PA[j] = Ag + (size_t)(off + rc) * INTER + kc * 8;
            PB[j] = Bg + ((size_t)(e * HIDDEN + nt * 256 + row)) * INTER + kc * 8;
        }
    }

    // stage one half-tile (m: 0=A 1=B; kh region) of K-tile kt into buffer b.
    auto stage = [&](int m, int kh, int kt, int b) {
        __hip_bfloat16* L = smem + (size_t)(((b << 2) | (m << 1) | kh) << 13);
        const __hip_bfloat16* s0 = (m ? PB[0] : PA[0]) + kt * 64 + kh * 32;
        const __hip_bfloat16* s1 = (m ? PB[1] : PA[1]) + kt * 64 + kh * 32;
        lds_cp16(s0, L + tid * 8);
        lds_cp16(s1, L + (512 + tid) * 8);
    };

    f32x4 acc[8][4];
    #pragma unroll
    for (int mf = 0; mf < 8; ++mf)
        #pragma unroll
        for (int nf = 0; nf < 4; ++nf) acc[mf][nf] = (f32x4)0.f;

    short8 afr[8], bfr[2];

    // prologue: tile 0 fully + tile 1 kh0; oldest 4 loads = [0 A-kh0],[0 B-kh0]
    stage(0, 0, 0, 0); stage(1, 0, 0, 0);
    stage(0, 1, 0, 0); stage(1, 1, 0, 0);
    stage(0, 0, 1, 1); stage(1, 0, 1, 1);
    W_V8; BAR;

    #pragma unroll 2
    for (int t = 0; t < NT - 2; ++t) {
        KTILE(t, 1, 1, W_V8, W_V8);
    }
    KTILE(NT - 2, 1, 0, W_V8, W_V4);
    KTILE(NT - 1, 0, 0, W_V0, W_NONE);
    W_V0; // drain any stragglers before LDS goes out of scope

    // epilogue: D col = lane&15 (B extent), row = (lane>>4)*4 + reg (A extent)
    if constexpr (WHICH == 1) {
        #pragma unroll
        for (int mf = 0; mf < 8; ++mf) {
            #pragma unroll
            for (int reg = 0; reg < 4; ++reg) {
                int row = wm * 128 + mf * 16 + q * 4 + reg;
                int rg  = mt * 256 + row;
                if (rg < count) {
                    float wgt = slot_w[off + rg];
                    #pragma unroll
                    for (int g = 0; g < 2; ++g) {
                        float gv = acc[mf][2 * g + 0][reg];
                        float uv = acc[mf][2 * g + 1][reg];
                        float hv = gv / (1.f + __expf(-gv)) * uv * wgt;
                        Out[(size_t)(off + rg) * INTER + nt * 128 + (wn * 2 + g) * 16 + l15] =
                            __float2bfloat16(hv);
                    }
                }
            }
        }
    } else {
        #pragma unroll
        for (int mf = 0; mf < 8; ++mf) {
            #pragma unroll
            for (int reg = 0; reg < 4; ++reg) {
                int row = wm * 128 + mf * 16 + q * 4 + reg;
                int rg  = mt * 256 + row;
                if (rg < count) {
                    size_t base = (size_t)(off + rg) * HIDDEN + nt * 256 + wn * 64;
                    #pragma unroll
                    for (int nf = 0; nf < 4; ++nf)
                        Out[base + nf * 16 + l15] = __float2bfloat16(acc[mf][nf][reg]);
                }
            }
        }
    }
}

// ---------------- combine ----------------
__global__ void combine_kernel(const __hip_bfloat16* __restrict__ eo,
                               const int* __restrict__ tok2slot,
                               float* __restrict__ out) {
    int idx = blockIdx.x * blockDim.x + threadIdx.x;
    int t = idx >> 8;
    int c = (idx & 255) * 8;
    int s1 = tok2slot[t * 2], s2 = tok2slot[t * 2 + 1];
    short8 v1 = *(const short8*)(eo + (size_t)s1 * HIDDEN + c);
    short8 v2 = *(const short8*)(eo + (size_t)s2 * HIDDEN + c);
    float4 o0, o1;
    o0.x = bf2f(v1[0]) + bf2f(v2[0]); o0.y = bf2f(v1[1]) + bf2f(v2[1]);
    o0.z = bf2f(v1[2]) + bf2f(v2[2]); o0.w = bf2f(v1[3]) + bf2f(v2[3]);
    o1.x = bf2f(v1[4]) + bf2f(v2[4]); o1.y = bf2f(v1[5]) + bf2f(v2[5]);
    o1.z = bf2f(v1[6]) + bf2f(v2[6]); o1.w = bf2f(v1[7]) + bf2f(v2[7]);
    float* op = out + (size_t)t * HIDDEN + c;
    *(float4*)op = o0;
    *(float4*)(op + 4) = o1;
}

extern "C" void kernel_launch(void* const* d_in, const int* in_sizes, int n_in,
                              void* d_out, int out_size, void* d_ws, size_t ws_size,
                              hipStream_t stream)
{
    (void)in_sizes; (void)n_in; (void)ws_size; (void)out_size;
    const float* x  = (const float*)d_in[0];
    const float* rw = (const float*)d_in[1];
    const float* gu = (const float*)d_in[2];
    const float* dn = (const float*)d_in[3];

    char* p = (char*)d_ws;
    auto take = [&](size_t bytes) { char* r = p; p += (bytes + 255) & ~(size_t)255; return r; };
    __hip_bfloat16* xb  = (__hip_bfloat16*)take((size_t)NTOK * HIDDEN * 2);
    __hip_bfloat16* gub = (__hip_bfloat16*)take((size_t)NE * 2 * INTER * HIDDEN * 2);
    __hip_bfloat16* dnb = (__hip_bfloat16*)take((size_t)NE * HIDDEN * INTER * 2);
    __hip_bfloat16* hbuf= (__hip_bfloat16*)take((size_t)(2 * NTOK + 256) * INTER * 2);
    int*   counts   = (int*)take(64);
    int*   offsets  = (int*)take(64);
    int*   cursor   = (int*)take(64);
    int*   ntile    = (int*)take(64);
    int*   tiles    = (int*)take(MAXT * 4);
    int*   topk_e   = (int*)take((size_t)NTOK * 2 * 4);
    float* topk_w   = (float*)take((size_t)NTOK * 2 * 4);
    int*   slot_tid = (int*)take((size_t)(2 * NTOK + 256) * 4);
    float* slot_w   = (float*)take((size_t)(2 * NTOK + 256) * 4);
    int*   tok2slot = (int*)take((size_t)NTOK * 2 * 4);
    // eo aliases gub scratch: gub dead after gemm1, eo (33.5 MB) < gub (92.3 MB)
    __hip_bfloat16* eo = gub;

    hipFuncSetAttribute((const void*)moe_gemm<1>,
                        hipFuncAttributeMaxDynamicSharedMemorySize, 131072);
    hipFuncSetAttribute((const void*)moe_gemm<2>,
                        hipFuncAttributeMaxDynamicSharedMemorySize, 131072);

    hipMemsetAsync(counts, 0, 64, stream);

    cvt_w_kernel<<<dim3((C1 + C2) / 256), 256, 0, stream>>>(gu, dn, gub, dnb);

    router_kernel<<<dim3(NTOK / 4), 256, 0, stream>>>(x, rw, counts, topk_e, topk_w, xb);
    scan_kernel<<<dim3(1), 64, 0, stream>>>(counts, offsets, cursor, tiles, ntile);
    scatter_kernel<<<dim3((NTOK * 2) / 256), 256, 0, stream>>>(topk_e, topk_w, cursor,
                                                               slot_tid, slot_w, tok2slot);

    moe_gemm<1><<<dim3(INTER / 128, MAXT), 512, 131072, stream>>>(
        xb, gub, counts, offsets, tiles, ntile, slot_tid, slot_w, hbuf);
    moe_gemm<2><<<dim3(HIDDEN / 256, MAXT), 512, 131072, stream>>>(
        hbuf, dnb, counts, offsets, tiles, ntile, slot_tid, slot_w, eo);
    combine_kernel<<<dim3(NTOK * HIDDEN / 8 / 256), 256, 0, stream>>>(
        eo, tok2slot, (float*)d_out);
}